// Round 2
// baseline (446.248 us; speedup 1.0000x reference)
//
#include <hip/hip_runtime.h>

// CostTokenizer R2: latency-bound fix. 16x4 px tiles, 4 waves/block split the
// channel dim (wave-private halo, no barriers in C-loop), LDS 2-slice reduce,
// then 49->192 contraction split 4-ways over d (48 d per thread, scalar w).
//
//  corr[k] = sum_c f1[c,h,w] * f2[c, (h-dy)%H, (w-dx)%W], k = (dy+3)*7 + (dx+3)
//  tok[t,b,d,h,w] = b[d] + (1/sqrt(C)) * sum_k corr[k] * w[k,d]

#define TD 192

template<int C, int H, int W>
__device__ __forceinline__ void level_tile(
    const float* __restrict__ lvl, const float* __restrict__ wm,
    const float* __restrict__ bias, float* __restrict__ out,
    int pair, int tY, int tX, float scale,
    float4* __restrict__ hs, float* __restrict__ sc)
{
    const int HW = H * W;
    const int t  = pair >> 1, bb = pair & 1;
    const float* f1 = lvl + (t * 2 + bb) * C * HW;
    const float* f2 = lvl + ((t + 1) * 2 + bb) * C * HW;

    const int tid  = threadIdx.x;
    const int lane = tid & 63;
    const int g    = tid >> 6;          // wave id: channel group (ph1) / d group (ph3)
    const int tx   = lane & 15, ty = lane >> 4;
    const int x0   = tX * 16, y0 = tY * 4;
    const int x    = x0 + tx,  y  = y0 + ty;

    float acc[49];
#pragma unroll
    for (int k = 0; k < 49; ++k) acc[k] = 0.f;

    float4* h = hs + g * 230;           // wave-private: 10 rows x (22+1 pad) float4

    // ---- phase 1: correlation, wave-synchronous (no __syncthreads) ----
    const int NCH = C / 16;             // 4-channel chunks per group
    for (int cg = 0; cg < NCH; ++cg) {
        const float* f2c = f2 + (g * (C / 4) + cg * 4) * HW;
        for (int p = lane; p < 220; p += 64) {
            int r = p / 22, cc = p - r * 22;
            int gy = y0 - 3 + r;  if (gy < 0) gy += H;  if (gy >= H) gy -= H;
            int gx = x0 - 3 + cc; if (gx < 0) gx += W;  if (gx >= W) gx -= W;
            const float* s = f2c + gy * W + gx;
            float4 v; v.x = s[0]; v.y = s[HW]; v.z = s[2 * HW]; v.w = s[3 * HW];
            h[r * 23 + cc] = v;
        }
        const float* f1c = f1 + (g * (C / 4) + cg * 4) * HW + y * W + x;
        float a0 = f1c[0], a1 = f1c[HW], a2 = f1c[2 * HW], a3 = f1c[3 * HW];
        // same-wave LDS RAW: compiler-inserted lgkmcnt waits cover it
#pragma unroll
        for (int a = 0; a < 7; ++a) {
#pragma unroll
            for (int b = 0; b < 7; ++b) {
                float4 v = h[(ty + 6 - a) * 23 + (tx + 6 - b)];
                float s = acc[a * 7 + b];
                s = fmaf(a0, v.x, s);
                s = fmaf(a1, v.y, s);
                s = fmaf(a2, v.z, s);
                s = fmaf(a3, v.w, s);
                acc[a * 7 + b] = s;
            }
        }
    }

    // ---- phase 2: cross-wave reduction into 2 LDS slices ----
    float* s0 = sc;                     // [49][64]
    float* s1 = sc + 49 * 64;
    if (g >= 2) {
        float* dst = (g == 2) ? s0 : s1;
#pragma unroll
        for (int k = 0; k < 49; ++k) dst[k * 64 + lane] = acc[k];
    }
    __syncthreads();
    if (g < 2) {
        float* dst = (g == 0) ? s0 : s1;
#pragma unroll
        for (int k = 0; k < 49; ++k) dst[k * 64 + lane] += acc[k];
    }
    __syncthreads();

    // ---- phase 3: 49 -> 192 contraction, wave g owns d in [g*48, g*48+48) ----
    const int dbase = __builtin_amdgcn_readfirstlane(g * 48);
    float sacc[48];
#pragma unroll
    for (int j = 0; j < 48; ++j) sacc[j] = bias[dbase + j];
    for (int k = 0; k < 49; ++k) {
        float c = (s0[k * 64 + lane] + s1[k * 64 + lane]) * scale;
        const float* wr = wm + k * TD + dbase;   // uniform -> s_load
#pragma unroll
        for (int j = 0; j < 48; ++j) sacc[j] = fmaf(wr[j], c, sacc[j]);
    }
    float* op = out + (pair * TD + dbase) * HW + y * W + x;
#pragma unroll
    for (int j = 0; j < 48; ++j) op[j * HW] = sacc[j];
}

__global__ __launch_bounds__(256, 4)
void cost_tokenizer(const float* __restrict__ l1, const float* __restrict__ l2,
                    const float* __restrict__ l3,
                    const float* __restrict__ w1, const float* __restrict__ b1,
                    const float* __restrict__ w2, const float* __restrict__ b2,
                    const float* __restrict__ w3, const float* __restrict__ b3,
                    float* __restrict__ out)
{
    __shared__ float4 hs[4 * 230];      // 14.7 KB wave-private halos
    __shared__ float  sc[2 * 49 * 64];  // 25.1 KB reduction slices
    int bid = blockIdx.x;
    // heavy levels first: L3 (12 chunks/wave), L2 (8), L1 (4)
    if (bid < 64) {
        int r = bid;                    // L3: 4 pairs x (8 tY x 2 tX)
        level_tile<192, 32, 32>(l3, w3, b3, out + 15728640,
                                r >> 4, (r >> 1) & 7, r & 1,
                                0.072168783648703216f, hs, sc);
    } else if (bid < 320) {
        int r = bid - 64;               // L2: 4 pairs x (16 tY x 4 tX)
        level_tile<128, 64, 64>(l2, w2, b2, out + 12582912,
                                r >> 6, (r >> 2) & 15, r & 3,
                                0.088388347648318447f, hs, sc);
    } else {
        int r = bid - 320;              // L1: 4 pairs x (32 tY x 8 tX)
        level_tile<64, 128, 128>(l1, w1, b1, out,
                                 r >> 8, (r >> 3) & 31, r & 7,
                                 0.125f, hs, sc);
    }
}

extern "C" void kernel_launch(void* const* d_in, const int* in_sizes, int n_in,
                              void* d_out, int out_size, void* d_ws, size_t ws_size,
                              hipStream_t stream)
{
    const float* l1 = (const float*)d_in[0];
    const float* l2 = (const float*)d_in[1];
    const float* l3 = (const float*)d_in[2];
    const float* w1 = (const float*)d_in[3];
    const float* b1 = (const float*)d_in[4];
    const float* w2 = (const float*)d_in[5];
    const float* b2 = (const float*)d_in[6];
    const float* w3 = (const float*)d_in[7];
    const float* b3 = (const float*)d_in[8];
    float* out = (float*)d_out;

    hipLaunchKernelGGL(cost_tokenizer, dim3(1344), dim3(256), 0, stream,
                       l1, l2, l3, w1, b1, w2, b2, w3, b3, out);
}

// Round 3
// 160.959 us; speedup vs baseline: 2.7724x; 2.7724x over previous
//
#include <hip/hip_runtime.h>

// CostTokenizer R3: R2 structure (16x4 tiles, 4 waves split channels, LDS
// reduce, d-split contraction) with the R2 scratch-spill fixed:
//   - launch_bounds(256,2): 256-reg unified budget (R2's (256,4)->128 spilled
//     acc[49]/sacc[48] to scratch -> 990 MB HBM traffic, 8% VALUBusy)
//   - rolled outer loops + hoisted halo offsets to keep pressure ~70 regs
//
//  corr[k] = sum_c f1[c,h,w] * f2[c, (h-dy)%H, (w-dx)%W], k = (dy+3)*7 + (dx+3)
//  tok[t,b,d,h,w] = b[d] + (1/sqrt(C)) * sum_k corr[k] * w[k,d]

#define TD 192

template<int C, int H, int W>
__device__ __forceinline__ void level_tile(
    const float* __restrict__ lvl, const float* __restrict__ wm,
    const float* __restrict__ bias, float* __restrict__ out,
    int pair, int tY, int tX, float scale,
    float4* __restrict__ hs, float* __restrict__ sc)
{
    const int HW = H * W;
    const int t  = pair >> 1, bb = pair & 1;
    const float* f1 = lvl + (t * 2 + bb) * C * HW;
    const float* f2 = lvl + ((t + 1) * 2 + bb) * C * HW;

    const int tid  = threadIdx.x;
    const int lane = tid & 63;
    const int g    = tid >> 6;          // wave id: channel group (ph1) / d group (ph3)
    const int tx   = lane & 15, ty = lane >> 4;
    const int x0   = tX * 16, y0 = tY * 4;
    const int x    = x0 + tx,  y  = y0 + ty;

    float4* h = hs + g * 230;           // wave-private: 10 rows x (22+1 pad) float4

    // hoisted halo staging offsets (constant across chunks; f2c bumps by 4*HW)
    int goff[4], loff[4];
#pragma unroll
    for (int i = 0; i < 4; ++i) {
        int p = lane + i * 64;          // i==3 valid only for lane<28 (p<220)
        int r = p / 22, cc = p - r * 22;
        int gy = y0 - 3 + r;  if (gy < 0) gy += H;  if (gy >= H) gy -= H;
        int gx = x0 - 3 + cc; if (gx < 0) gx += W;  if (gx >= W) gx -= W;
        goff[i] = gy * W + gx;
        loff[i] = r * 23 + cc;
    }

    float acc[49];
#pragma unroll
    for (int k = 0; k < 49; ++k) acc[k] = 0.f;

    // ---- phase 1: correlation, wave-synchronous (no __syncthreads) ----
    const int NCH = C / 16;             // 4-channel chunks per wave
    const float* f2c = f2 + g * (C / 4) * HW;
    const float* f1c = f1 + g * (C / 4) * HW + y * W + x;
#pragma unroll 1
    for (int cg = 0; cg < NCH; ++cg) {
#pragma unroll
        for (int i = 0; i < 4; ++i) {
            if (i < 3 || lane < 28) {
                const float* s = f2c + goff[i];
                float4 v; v.x = s[0]; v.y = s[HW]; v.z = s[2 * HW]; v.w = s[3 * HW];
                h[loff[i]] = v;
            }
        }
        float a0 = f1c[0], a1 = f1c[HW], a2 = f1c[2 * HW], a3 = f1c[3 * HW];
        f2c += 4 * HW; f1c += 4 * HW;
        // same-wave LDS RAW: compiler-inserted lgkmcnt waits cover it
#pragma unroll
        for (int a = 0; a < 7; ++a) {
#pragma unroll
            for (int b = 0; b < 7; ++b) {
                float4 v = h[(ty + 6 - a) * 23 + (tx + 6 - b)];
                float s = acc[a * 7 + b];
                s = fmaf(a0, v.x, s);
                s = fmaf(a1, v.y, s);
                s = fmaf(a2, v.z, s);
                s = fmaf(a3, v.w, s);
                acc[a * 7 + b] = s;
            }
        }
    }

    // ---- phase 2: cross-wave reduction into 2 LDS slices ----
    float* s0 = sc;                     // [49][64]
    float* s1 = sc + 49 * 64;
    if (g >= 2) {
        float* dst = (g == 2) ? s0 : s1;
#pragma unroll
        for (int k = 0; k < 49; ++k) dst[k * 64 + lane] = acc[k];
    }
    __syncthreads();
    if (g < 2) {
        float* dst = (g == 0) ? s0 : s1;
#pragma unroll
        for (int k = 0; k < 49; ++k) dst[k * 64 + lane] += acc[k];
    }
    __syncthreads();

    // ---- phase 3: 49 -> 192 contraction, wave g owns d in [g*48, g*48+48) ----
    const int dbase = __builtin_amdgcn_readfirstlane(g * 48);
    float sacc[48];
#pragma unroll
    for (int j = 0; j < 48; ++j) sacc[j] = bias[dbase + j];
#pragma unroll 1
    for (int k = 0; k < 49; ++k) {
        float c = (s0[k * 64 + lane] + s1[k * 64 + lane]) * scale;
        const float* wr = wm + k * TD + dbase;   // wave-uniform -> s_load
#pragma unroll
        for (int j = 0; j < 48; ++j) sacc[j] = fmaf(wr[j], c, sacc[j]);
    }
    float* op = out + (pair * TD + dbase) * HW + y * W + x;
#pragma unroll
    for (int j = 0; j < 48; ++j) op[j * HW] = sacc[j];
}

__global__ __launch_bounds__(256, 2)
void cost_tokenizer(const float* __restrict__ l1, const float* __restrict__ l2,
                    const float* __restrict__ l3,
                    const float* __restrict__ w1, const float* __restrict__ b1,
                    const float* __restrict__ w2, const float* __restrict__ b2,
                    const float* __restrict__ w3, const float* __restrict__ b3,
                    float* __restrict__ out)
{
    __shared__ float4 hs[4 * 230];      // 14.7 KB wave-private halos
    __shared__ float  sc[2 * 49 * 64];  // 25.1 KB reduction slices
    int bid = blockIdx.x;
    // heavy levels first: L3 (12 chunks/wave), L2 (8), L1 (4)
    if (bid < 64) {
        int r = bid;                    // L3: 4 pairs x (8 tY x 2 tX)
        level_tile<192, 32, 32>(l3, w3, b3, out + 15728640,
                                r >> 4, (r >> 1) & 7, r & 1,
                                0.072168783648703216f, hs, sc);
    } else if (bid < 320) {
        int r = bid - 64;               // L2: 4 pairs x (16 tY x 4 tX)
        level_tile<128, 64, 64>(l2, w2, b2, out + 12582912,
                                r >> 6, (r >> 2) & 15, r & 3,
                                0.088388347648318447f, hs, sc);
    } else {
        int r = bid - 320;              // L1: 4 pairs x (32 tY x 8 tX)
        level_tile<64, 128, 128>(l1, w1, b1, out,
                                 r >> 8, (r >> 3) & 31, r & 7,
                                 0.125f, hs, sc);
    }
}

extern "C" void kernel_launch(void* const* d_in, const int* in_sizes, int n_in,
                              void* d_out, int out_size, void* d_ws, size_t ws_size,
                              hipStream_t stream)
{
    const float* l1 = (const float*)d_in[0];
    const float* l2 = (const float*)d_in[1];
    const float* l3 = (const float*)d_in[2];
    const float* w1 = (const float*)d_in[3];
    const float* b1 = (const float*)d_in[4];
    const float* w2 = (const float*)d_in[5];
    const float* b2 = (const float*)d_in[6];
    const float* w3 = (const float*)d_in[7];
    const float* b3 = (const float*)d_in[8];
    float* out = (float*)d_out;

    hipLaunchKernelGGL(cost_tokenizer, dim3(1344), dim3(256), 0, stream,
                       l1, l2, l3, w1, b1, w2, b2, w3, b3, out);
}